// Round 6
// baseline (902.947 us; speedup 1.0000x reference)
//
#include <hip/hip_runtime.h>
#include <hip/hip_fp16.h>
#include <stdint.h>

#define B 64
#define T 512
#define D 256

typedef _Float16 f16;
typedef __attribute__((ext_vector_type(8))) _Float16 f16x8;
typedef __attribute__((ext_vector_type(4))) _Float16 f16x4;
typedef __attribute__((ext_vector_type(2))) _Float16 f16x2;
typedef __attribute__((ext_vector_type(4))) float f32x4;

// ---------------------------------------------------------------- K0: weight f32->f16 converts
__global__ void k_convert(const float* __restrict__ W1, const float* __restrict__ Wr,
                          const float* __restrict__ Wg,
                          f16* __restrict__ W1h, f16* __restrict__ Wrh, f16* __restrict__ Wgh)
{
  const int64_t n1 = 256 * 1024, n2 = 65536, n3 = 65536;
  int64_t stride = (int64_t)gridDim.x * blockDim.x;
  for (int64_t i = (int64_t)blockIdx.x * blockDim.x + threadIdx.x; i < n1 + n2 + n3; i += stride) {
    if (i < n1)           W1h[i] = (f16)W1[i];
    else if (i < n1 + n2) Wrh[i - n1] = (f16)Wr[i - n1];
    else                  Wgh[i - n1 - n2] = (f16)Wg[i - n1 - n2];
  }
}

// ---------------------------------------------------------------- K1: attention logits (MFMA f16)
__global__ __launch_bounds__(256, 2) void k_attn(
    const float* __restrict__ facts, const float* __restrict__ queries,
    const float* __restrict__ m_old, const f16* __restrict__ W1h,
    const float* __restrict__ W1_b, const float* __restrict__ W2_w,
    const float* __restrict__ W2_b, float* __restrict__ Zlog)
{
  const int b = blockIdx.y;
  const int t0 = blockIdx.x * 32;
  const int tid = threadIdx.x;
  const int lane = tid & 63;
  const int wave = tid >> 6;
  const int lr = lane & 15;
  const int lg = lane >> 4;

  __shared__ float q_s[D], m_s[D];
  __shared__ __align__(16) char zbuf[32 * 2048];   // 32 rows x 1024 f16 (XOR-swizzled)
  __shared__ float part[4][32];

  q_s[tid] = queries[b * D + tid];
  m_s[tid] = m_old[b * D + tid];
  __syncthreads();

  for (int e = tid; e < 32 * 128; e += 256) {
    int t = e >> 7;
    int j2 = e & 127;
    int j = j2 * 2;
    const float2 f2 = *(const float2*)(facts + ((int64_t)(b * T) + t0 + t) * D + j);
    float q0 = q_s[j], q1 = q_s[j + 1], mm0 = m_s[j], mm1 = m_s[j + 1];
    f16x2 z0; z0[0] = (f16)(f2.x * q0);        z0[1] = (f16)(f2.y * q1);
    f16x2 z1; z1[0] = (f16)(f2.x * mm0);       z1[1] = (f16)(f2.y * mm1);
    f16x2 z2; z2[0] = (f16)fabsf(f2.x - q0);   z2[1] = (f16)fabsf(f2.y - q1);
    f16x2 z3; z3[0] = (f16)fabsf(f2.x - mm0);  z3[1] = (f16)fabsf(f2.y - mm1);
    int xr = (t & 7) << 4;
    int base = t * 2048;
    *(f16x2*)(zbuf + ((base + (0 * 128 + j2) * 4) ^ xr)) = z0;
    *(f16x2*)(zbuf + ((base + (1 * 128 + j2) * 4) ^ xr)) = z1;
    *(f16x2*)(zbuf + ((base + (2 * 128 + j2) * 4) ^ xr)) = z2;
    *(f16x2*)(zbuf + ((base + (3 * 128 + j2) * 4) ^ xr)) = z3;
  }
  __syncthreads();

  const int n0 = wave * 64;
  f32x4 acc[2][4];
  #pragma unroll
  for (int i = 0; i < 2; ++i)
    #pragma unroll
    for (int j = 0; j < 4; ++j) acc[i][j] = (f32x4){0.f, 0.f, 0.f, 0.f};

  #pragma unroll 2
  for (int ks = 0; ks < 32; ++ks) {
    f16x8 af[2];
    #pragma unroll
    for (int mt = 0; mt < 2; ++mt) {
      int row = mt * 16 + lr;
      int byte = (row * 2048 + ks * 64 + lg * 16) ^ ((row & 7) << 4);
      af[mt] = *(const f16x8*)(zbuf + byte);
    }
    #pragma unroll
    for (int nt = 0; nt < 4; ++nt) {
      int a = n0 + nt * 16 + lr;
      f16x8 bf = *(const f16x8*)(W1h + (int64_t)a * 1024 + ks * 32 + lg * 8);
      acc[0][nt] = __builtin_amdgcn_mfma_f32_16x16x32_f16(af[0], bf, acc[0][nt], 0, 0, 0);
      acc[1][nt] = __builtin_amdgcn_mfma_f32_16x16x32_f16(af[1], bf, acc[1][nt], 0, 0, 0);
    }
  }

  float pr[2][4] = {{0.f, 0.f, 0.f, 0.f}, {0.f, 0.f, 0.f, 0.f}};
  #pragma unroll
  for (int nt = 0; nt < 4; ++nt) {
    int a = n0 + nt * 16 + lr;
    float b1 = W1_b[a];
    float w2 = W2_w[a];
    #pragma unroll
    for (int mt = 0; mt < 2; ++mt)
      #pragma unroll
      for (int r = 0; r < 4; ++r)
        pr[mt][r] += tanhf(acc[mt][nt][r] + b1) * w2;
  }
  #pragma unroll
  for (int mt = 0; mt < 2; ++mt)
    #pragma unroll
    for (int r = 0; r < 4; ++r) {
      float v = pr[mt][r];
      v += __shfl_xor(v, 1, 64);
      v += __shfl_xor(v, 2, 64);
      v += __shfl_xor(v, 4, 64);
      v += __shfl_xor(v, 8, 64);
      pr[mt][r] = v;
    }
  if ((lane & 15) == 0) {
    #pragma unroll
    for (int mt = 0; mt < 2; ++mt)
      #pragma unroll
      for (int r = 0; r < 4; ++r)
        part[wave][mt * 16 + lg * 4 + r] = pr[mt][r];
  }
  __syncthreads();
  if (tid < 32)
    Zlog[b * T + t0 + tid] = part[0][tid] + part[1][tid] + part[2][tid] + part[3][tid] + W2_b[0];
}

// ---------------------------------------------------------------- K2: fact projections (MFMA f16, f32 out)
// Fr = facts@Wr^T + Ur_b ; Fg = facts@Wg^T   (facts converted f32->f16 inline)
__global__ __launch_bounds__(256, 2) void k_factproj(
    const float* __restrict__ facts, const f16* __restrict__ Wrh, const f16* __restrict__ Wgh,
    const float* __restrict__ Ur_b, float* __restrict__ Fr, float* __restrict__ Fg)
{
  const int b = blockIdx.y;
  const int t0 = blockIdx.x * 64;
  const int tid = threadIdx.x;
  const int lane = tid & 63;
  const int wave = tid >> 6;
  const int lr = lane & 15;
  const int lg = lane >> 4;

  __shared__ __align__(16) char albuf[64 * 512];   // 64 rows x 256 f16, swizzled

  for (int c = tid; c < 64 * 32; c += 256) {
    int row = c >> 5;
    int kc = c & 31;
    const float* src = facts + ((int64_t)(b * T) + t0 + row) * D + kc * 8;
    float4 x0 = *(const float4*)src;
    float4 x1 = *(const float4*)(src + 4);
    f16x8 v;
    v[0] = (f16)x0.x; v[1] = (f16)x0.y; v[2] = (f16)x0.z; v[3] = (f16)x0.w;
    v[4] = (f16)x1.x; v[5] = (f16)x1.y; v[6] = (f16)x1.z; v[7] = (f16)x1.w;
    int byte = (row * 512 + kc * 16) ^ ((row & 7) << 4);
    *(f16x8*)(albuf + byte) = v;
  }
  __syncthreads();

  f32x4 accr[16], accg[16];
  #pragma unroll
  for (int i = 0; i < 16; ++i) { accr[i] = (f32x4){0.f,0.f,0.f,0.f}; accg[i] = (f32x4){0.f,0.f,0.f,0.f}; }

  const int arow = wave * 16 + lr;
  #pragma unroll 2
  for (int ks = 0; ks < 8; ++ks) {
    int byte = (arow * 512 + ks * 64 + lg * 16) ^ ((arow & 7) << 4);
    f16x8 af = *(const f16x8*)(albuf + byte);
    #pragma unroll
    for (int nt = 0; nt < 16; ++nt) {
      int a = nt * 16 + lr;
      f16x8 br = *(const f16x8*)(Wrh + a * 256 + ks * 32 + lg * 8);
      f16x8 bg = *(const f16x8*)(Wgh + a * 256 + ks * 32 + lg * 8);
      accr[nt] = __builtin_amdgcn_mfma_f32_16x16x32_f16(af, br, accr[nt], 0, 0, 0);
      accg[nt] = __builtin_amdgcn_mfma_f32_16x16x32_f16(af, bg, accg[nt], 0, 0, 0);
    }
  }

  #pragma unroll
  for (int nt = 0; nt < 16; ++nt) {
    int col = nt * 16 + lr;
    float urb = Ur_b[col];
    #pragma unroll
    for (int r = 0; r < 4; ++r) {
      int t = t0 + wave * 16 + lg * 4 + r;
      int64_t off = ((int64_t)(b * T) + t) * D + col;
      Fr[off] = accr[nt][r] + urb;
      Fg[off] = accg[nt][r];
    }
  }
}

// ---------------------------------------------------------------- K3: masked softmax, 1 wave per batch
__global__ void k_softmax2(const float* __restrict__ Zlog, const int* __restrict__ num_facts,
                           float* __restrict__ g)
{
  const int b = blockIdx.x;
  const int lane = threadIdx.x;       // 64 threads
  const int nf = num_facts[b];
  float v[8];
  float mx = -INFINITY;
  #pragma unroll
  for (int j = 0; j < 8; ++j) {
    int t = j * 64 + lane;
    float z = Zlog[b * T + t];
    v[j] = (t < nf) ? z : -INFINITY;
    mx = fmaxf(mx, v[j]);
  }
  #pragma unroll
  for (int s = 1; s < 64; s <<= 1) mx = fmaxf(mx, __shfl_xor(mx, s, 64));
  float e[8];
  float sum = 0.f;
  #pragma unroll
  for (int j = 0; j < 8; ++j) {
    int t = j * 64 + lane;
    e[j] = (t < nf) ? __expf(v[j] - mx) : 0.f;
    sum += e[j];
  }
  #pragma unroll
  for (int s = 1; s < 64; s <<= 1) sum += __shfl_xor(sum, s, 64);
  float inv = 1.f / sum;
  #pragma unroll
  for (int j = 0; j < 8; ++j)
    g[b * T + j * 64 + lane] = e[j] * inv;
}

// ---------------------------------------------------------------- K4: AGRU scan v4 — MFMA, 16 batches/WG
// 4 WGs x 16 batches. Weights as A-fragments in VGPRs (rows = weight rows).
// h[16 batches][256] f16 in ping-pong LDS, read as B-fragments (B-row = batch).
// D[row=wrow][col=batch]; h_old/fr/fg live in D-layout registers.
// g==0 for t>=nf_b (softmax) freezes finished batches exactly.
__global__ __launch_bounds__(512) void k_scan_v4(
    const float* __restrict__ Fr, const float* __restrict__ Fg, const float* __restrict__ g,
    const int* __restrict__ num_facts, const float* __restrict__ Ur_w,
    const float* __restrict__ Ug_w, const float* __restrict__ Ug_b,
    const float* __restrict__ m_old, float* __restrict__ c_out)
{
  const int b0 = blockIdx.x * 16;
  const int tid = threadIdx.x;
  const int lane = tid & 63;
  const int wave = tid >> 6;          // 0..7 -> rows 32*wave .. +31
  const int lr = lane & 15;           // A: weight row low bits | B/D: batch
  const int lg = lane >> 4;           // k-subgroup / row-subgroup

  __shared__ __align__(16) char hbuf[2][16 * 512];   // [batch][k] f16, XOR-swizzled

  // ---- preload weights as A-fragments: aX[rt][kt], rt in {0,1} (rows wave*32+rt*16+lr)
  f16x8 aR[2][8], aG[2][8];
  #pragma unroll
  for (int rt = 0; rt < 2; ++rt) {
    int arow = wave * 32 + rt * 16 + lr;
    #pragma unroll
    for (int kt = 0; kt < 8; ++kt) {
      const float* ur = Ur_w + (int64_t)arow * 256 + kt * 32 + lg * 8;
      const float* ug = Ug_w + (int64_t)arow * 256 + kt * 32 + lg * 8;
      float4 u0 = *(const float4*)ur, u1 = *(const float4*)(ur + 4);
      float4 v0 = *(const float4*)ug, v1 = *(const float4*)(ug + 4);
      f16x8 fa, fb;
      fa[0]=(f16)u0.x; fa[1]=(f16)u0.y; fa[2]=(f16)u0.z; fa[3]=(f16)u0.w;
      fa[4]=(f16)u1.x; fa[5]=(f16)u1.y; fa[6]=(f16)u1.z; fa[7]=(f16)u1.w;
      fb[0]=(f16)v0.x; fb[1]=(f16)v0.y; fb[2]=(f16)v0.z; fb[3]=(f16)v0.w;
      fb[4]=(f16)v1.x; fb[5]=(f16)v1.y; fb[6]=(f16)v1.z; fb[7]=(f16)v1.w;
      aR[rt][kt] = fa;
      aG[rt][kt] = fb;
    }
  }

  // ---- per-lane D-layout state: (batch=lr, rows wave*32 + rt*16 + lg*4 + r)
  const int rbase = wave * 32 + lg * 4;
  float4 ho[2], ugb[2];
  #pragma unroll
  for (int rt = 0; rt < 2; ++rt) {
    ho[rt]  = *(const float4*)(m_old + (int64_t)(b0 + lr) * 256 + rbase + rt * 16);
    ugb[rt] = *(const float4*)(Ug_b + rbase + rt * 16);
  }

  // ---- nfmax over the WG's 16 batches
  int nfmax = 0;
  #pragma unroll
  for (int j = 0; j < 16; ++j) nfmax = max(nfmax, num_facts[b0 + j]);

  // ---- write h0 into buf0 (layout [batch][k], byte ^ ((batch&7)<<4))
  const int swz = (lr & 7) << 4;
  #pragma unroll
  for (int rt = 0; rt < 2; ++rt) {
    f16x4 p;
    p[0] = (f16)ho[rt].x; p[1] = (f16)ho[rt].y; p[2] = (f16)ho[rt].z; p[3] = (f16)ho[rt].w;
    *(f16x4*)(&hbuf[0][0] + ((lr * 512 + (rbase + rt * 16) * 2) ^ swz)) = p;
  }

  // ---- input streams (D-layout): fr/fg float4 per rt, gt scalar per batch
  const float* frp = Fr + (int64_t)(b0 + lr) * T * D + rbase;
  const float* fgp = Fg + (int64_t)(b0 + lr) * T * D + rbase;
  const float* gpp = g + (b0 + lr) * T;
  float4 frv[2], fgv[2];
  float gtv;
  frv[0] = *(const float4*)(frp);       frv[1] = *(const float4*)(frp + 16);
  fgv[0] = *(const float4*)(fgp);       fgv[1] = *(const float4*)(fgp + 16);
  gtv = gpp[0];

  __syncthreads();

  for (int t = 0; t < nfmax; ++t) {
    // B-fragments from current buffer: lane = (batch=lr, k = kt*32 + lg*8)
    const char* hb = &hbuf[t & 1][0];
    f16x8 bf[8];
    #pragma unroll
    for (int kt = 0; kt < 8; ++kt)
      bf[kt] = *(const f16x8*)(hb + ((lr * 512 + kt * 64 + lg * 16) ^ swz));

    // prefetch next step inputs
    float4 nfr0 = {0,0,0,0}, nfr1 = {0,0,0,0}, nfg0 = {0,0,0,0}, nfg1 = {0,0,0,0};
    float ngt = 0.f;
    if (t + 1 < nfmax) {
      const float* fp = frp + (int64_t)(t + 1) * D;
      const float* gp2 = fgp + (int64_t)(t + 1) * D;
      nfr0 = *(const float4*)(fp);       nfr1 = *(const float4*)(fp + 16);
      nfg0 = *(const float4*)(gp2);      nfg1 = *(const float4*)(gp2 + 16);
      ngt = gpp[t + 1];
    }

    // MFMA: dR/dG[rt] = U[rows] . h[batches]
    f32x4 dR[2] = {{0,0,0,0},{0,0,0,0}}, dG[2] = {{0,0,0,0},{0,0,0,0}};
    #pragma unroll
    for (int kt = 0; kt < 8; ++kt) {
      dR[0] = __builtin_amdgcn_mfma_f32_16x16x32_f16(aR[0][kt], bf[kt], dR[0], 0, 0, 0);
      dR[1] = __builtin_amdgcn_mfma_f32_16x16x32_f16(aR[1][kt], bf[kt], dR[1], 0, 0, 0);
      dG[0] = __builtin_amdgcn_mfma_f32_16x16x32_f16(aG[0][kt], bf[kt], dG[0], 0, 0, 0);
      dG[1] = __builtin_amdgcn_mfma_f32_16x16x32_f16(aG[1][kt], bf[kt], dG[1], 0, 0, 0);
    }

    // nonlinear + blend (8 (row,batch) pairs per lane), write h_new to other buffer
    char* hn = &hbuf[(t + 1) & 1][0];
    #pragma unroll
    for (int rt = 0; rt < 2; ++rt) {
      float hr[4] = {ho[rt].x, ho[rt].y, ho[rt].z, ho[rt].w};
      float fr4[4] = {frv[rt].x, frv[rt].y, frv[rt].z, frv[rt].w};
      float fg4[4] = {fgv[rt].x, fgv[rt].y, fgv[rt].z, fgv[rt].w};
      float ub4[4] = {ugb[rt].x, ugb[rt].y, ugb[rt].z, ugb[rt].w};
      f16x4 p;
      #pragma unroll
      for (int r = 0; r < 4; ++r) {
        float xr = fr4[r] + dR[rt][r];                      // Ur_b folded in Fr
        float rr = __builtin_amdgcn_rcpf(1.f + __expf(-xr));
        float y  = fg4[r] + rr * (dG[rt][r] + ub4[r]);
        float e2 = __expf(y * 2.f);
        float ht = 1.f - 2.f * __builtin_amdgcn_rcpf(1.f + e2);
        float hn1 = hr[r] + gtv * (ht - hr[r]);
        hr[r] = hn1;
        p[r] = (f16)hn1;
      }
      ho[rt] = (float4){hr[0], hr[1], hr[2], hr[3]};
      *(f16x4*)(hn + ((lr * 512 + (rbase + rt * 16) * 2) ^ swz)) = p;
    }

    frv[0] = nfr0; frv[1] = nfr1;
    fgv[0] = nfg0; fgv[1] = nfg1;
    gtv = ngt;
    __syncthreads();
  }

  // ---- output c = h at exit (per-batch freeze already applied via g=0)
  *(float4*)(c_out + (int64_t)(b0 + lr) * 256 + rbase)      = ho[0];
  *(float4*)(c_out + (int64_t)(b0 + lr) * 256 + rbase + 16) = ho[1];
}

// ---------------------------------------------------------------- K5: m_new = relu(cat @ Wt^T + bt)
__global__ __launch_bounds__(256) void k_final2(
    const float* __restrict__ m_old, const float* __restrict__ c_ws,
    const float* __restrict__ queries, const float* __restrict__ Wt_w,
    const float* __restrict__ Wt_b, float* __restrict__ out)
{
  const int b = blockIdx.x;
  const int tid = threadIdx.x;
  __shared__ __align__(16) float cat_s[768];
  for (int e = tid; e < 768; e += 256) {
    float v = (e < 256) ? m_old[b * 256 + e]
            : (e < 512) ? c_ws[b * 256 + (e - 256)]
                        : queries[b * 256 + (e - 512)];
    cat_s[e] = v;
  }
  __syncthreads();
  const float* wrow = Wt_w + (int64_t)tid * 768;
  float acc = 0.f;
  #pragma unroll 8
  for (int k = 0; k < 768; k += 4) {
    float4 w = *(const float4*)(wrow + k);
    float4 c4 = *(const float4*)(cat_s + k);
    acc += w.x * c4.x + w.y * c4.y + w.z * c4.z + w.w * c4.w;
  }
  out[b * 256 + tid] = fmaxf(acc + Wt_b[tid], 0.f);
}

// ----------------------------------------------------------------
extern "C" void kernel_launch(void* const* d_in, const int* in_sizes, int n_in,
                              void* d_out, int out_size, void* d_ws, size_t ws_size,
                              hipStream_t stream)
{
  const float* queries   = (const float*)d_in[0];
  const float* facts     = (const float*)d_in[1];
  const int*   num_facts = (const int*)d_in[2];
  const float* m_old     = (const float*)d_in[3];
  const float* W1_w = (const float*)d_in[4];
  const float* W1_b = (const float*)d_in[5];
  const float* W2_w = (const float*)d_in[6];
  const float* W2_b = (const float*)d_in[7];
  const float* Wr_w = (const float*)d_in[8];
  const float* Ur_w = (const float*)d_in[9];
  const float* Ur_b = (const float*)d_in[10];
  const float* Wg_w = (const float*)d_in[11];
  const float* Ug_w = (const float*)d_in[12];
  const float* Ug_b = (const float*)d_in[13];
  const float* Wt_w = (const float*)d_in[14];
  const float* Wt_b = (const float*)d_in[15];
  float* out = (float*)d_out;

  char* p = (char*)d_ws;
  auto alloc = [&](size_t bytes) { char* r = p; p += (bytes + 255) & ~(size_t)255; return r; };
  f16*   W1h  = (f16*)alloc((size_t)256 * 1024 * 2);
  f16*   Wrh  = (f16*)alloc((size_t)65536 * 2);
  f16*   Wgh  = (f16*)alloc((size_t)65536 * 2);
  float* Zlog = (float*)alloc((size_t)B * T * 4);
  float* g    = (float*)alloc((size_t)B * T * 4);
  float* Fr   = (float*)alloc((size_t)B * T * D * 4);
  float* Fg   = (float*)alloc((size_t)B * T * D * 4);
  float* c_ws = (float*)alloc((size_t)B * D * 4);

  k_convert<<<dim3(768), dim3(256), 0, stream>>>(W1_w, Wr_w, Wg_w, W1h, Wrh, Wgh);
  k_attn<<<dim3(16, 64), dim3(256), 0, stream>>>(facts, queries, m_old, W1h, W1_b, W2_w, W2_b, Zlog);
  k_factproj<<<dim3(8, 64), dim3(256), 0, stream>>>(facts, Wrh, Wgh, Ur_b, Fr, Fg);
  k_softmax2<<<dim3(64), dim3(64), 0, stream>>>(Zlog, num_facts, g);
  k_scan_v4<<<dim3(4), dim3(512), 0, stream>>>(Fr, Fg, g, num_facts, Ur_w, Ug_w, Ug_b, m_old, c_ws);
  k_final2<<<dim3(64), dim3(256), 0, stream>>>(m_old, c_ws, queries, Wt_w, Wt_b, out);
}

// Round 7
// 883.667 us; speedup vs baseline: 1.0218x; 1.0218x over previous
//
#include <hip/hip_runtime.h>
#include <hip/hip_fp16.h>
#include <stdint.h>

#define B 64
#define T 512
#define D 256

typedef _Float16 f16;
typedef __attribute__((ext_vector_type(8))) _Float16 f16x8;
typedef __attribute__((ext_vector_type(4))) _Float16 f16x4;
typedef __attribute__((ext_vector_type(2))) _Float16 f16x2;
typedef __attribute__((ext_vector_type(4))) float f32x4;
typedef __attribute__((ext_vector_type(4))) unsigned int u32x4;

static __device__ __forceinline__ float dot2f(f16x2 a, f16x2 b, float c) {
  return __builtin_amdgcn_fdot2(a, b, c, false);
}
static __device__ __forceinline__ f16x2 as_h2(unsigned int u) {
  return __builtin_bit_cast(f16x2, u);
}

// ---------------------------------------------------------------- K0: weight f32->f16 converts
__global__ void k_convert(const float* __restrict__ W1, const float* __restrict__ Wr,
                          const float* __restrict__ Wg,
                          f16* __restrict__ W1h, f16* __restrict__ Wrh, f16* __restrict__ Wgh)
{
  const int64_t n1 = 256 * 1024, n2 = 65536, n3 = 65536;
  int64_t stride = (int64_t)gridDim.x * blockDim.x;
  for (int64_t i = (int64_t)blockIdx.x * blockDim.x + threadIdx.x; i < n1 + n2 + n3; i += stride) {
    if (i < n1)           W1h[i] = (f16)W1[i];
    else if (i < n1 + n2) Wrh[i - n1] = (f16)Wr[i - n1];
    else                  Wgh[i - n1 - n2] = (f16)Wg[i - n1 - n2];
  }
}

// ---------------------------------------------------------------- K1: attention logits (MFMA f16)
__global__ __launch_bounds__(256, 2) void k_attn(
    const float* __restrict__ facts, const float* __restrict__ queries,
    const float* __restrict__ m_old, const f16* __restrict__ W1h,
    const float* __restrict__ W1_b, const float* __restrict__ W2_w,
    const float* __restrict__ W2_b, float* __restrict__ Zlog)
{
  const int b = blockIdx.y;
  const int t0 = blockIdx.x * 32;
  const int tid = threadIdx.x;
  const int lane = tid & 63;
  const int wave = tid >> 6;
  const int lr = lane & 15;
  const int lg = lane >> 4;

  __shared__ float q_s[D], m_s[D];
  __shared__ __align__(16) char zbuf[32 * 2048];   // 32 rows x 1024 f16 (XOR-swizzled)
  __shared__ float part[4][32];

  q_s[tid] = queries[b * D + tid];
  m_s[tid] = m_old[b * D + tid];
  __syncthreads();

  for (int e = tid; e < 32 * 128; e += 256) {
    int t = e >> 7;
    int j2 = e & 127;
    int j = j2 * 2;
    const float2 f2 = *(const float2*)(facts + ((int64_t)(b * T) + t0 + t) * D + j);
    float q0 = q_s[j], q1 = q_s[j + 1], mm0 = m_s[j], mm1 = m_s[j + 1];
    f16x2 z0; z0[0] = (f16)(f2.x * q0);        z0[1] = (f16)(f2.y * q1);
    f16x2 z1; z1[0] = (f16)(f2.x * mm0);       z1[1] = (f16)(f2.y * mm1);
    f16x2 z2; z2[0] = (f16)fabsf(f2.x - q0);   z2[1] = (f16)fabsf(f2.y - q1);
    f16x2 z3; z3[0] = (f16)fabsf(f2.x - mm0);  z3[1] = (f16)fabsf(f2.y - mm1);
    int xr = (t & 7) << 4;
    int base = t * 2048;
    *(f16x2*)(zbuf + ((base + (0 * 128 + j2) * 4) ^ xr)) = z0;
    *(f16x2*)(zbuf + ((base + (1 * 128 + j2) * 4) ^ xr)) = z1;
    *(f16x2*)(zbuf + ((base + (2 * 128 + j2) * 4) ^ xr)) = z2;
    *(f16x2*)(zbuf + ((base + (3 * 128 + j2) * 4) ^ xr)) = z3;
  }
  __syncthreads();

  const int n0 = wave * 64;
  f32x4 acc[2][4];
  #pragma unroll
  for (int i = 0; i < 2; ++i)
    #pragma unroll
    for (int j = 0; j < 4; ++j) acc[i][j] = (f32x4){0.f, 0.f, 0.f, 0.f};

  #pragma unroll 2
  for (int ks = 0; ks < 32; ++ks) {
    f16x8 af[2];
    #pragma unroll
    for (int mt = 0; mt < 2; ++mt) {
      int row = mt * 16 + lr;
      int byte = (row * 2048 + ks * 64 + lg * 16) ^ ((row & 7) << 4);
      af[mt] = *(const f16x8*)(zbuf + byte);
    }
    #pragma unroll
    for (int nt = 0; nt < 4; ++nt) {
      int a = n0 + nt * 16 + lr;
      f16x8 bf = *(const f16x8*)(W1h + (int64_t)a * 1024 + ks * 32 + lg * 8);
      acc[0][nt] = __builtin_amdgcn_mfma_f32_16x16x32_f16(af[0], bf, acc[0][nt], 0, 0, 0);
      acc[1][nt] = __builtin_amdgcn_mfma_f32_16x16x32_f16(af[1], bf, acc[1][nt], 0, 0, 0);
    }
  }

  float pr[2][4] = {{0.f, 0.f, 0.f, 0.f}, {0.f, 0.f, 0.f, 0.f}};
  #pragma unroll
  for (int nt = 0; nt < 4; ++nt) {
    int a = n0 + nt * 16 + lr;
    float b1 = W1_b[a];
    float w2 = W2_w[a];
    #pragma unroll
    for (int mt = 0; mt < 2; ++mt)
      #pragma unroll
      for (int r = 0; r < 4; ++r)
        pr[mt][r] += tanhf(acc[mt][nt][r] + b1) * w2;
  }
  #pragma unroll
  for (int mt = 0; mt < 2; ++mt)
    #pragma unroll
    for (int r = 0; r < 4; ++r) {
      float v = pr[mt][r];
      v += __shfl_xor(v, 1, 64);
      v += __shfl_xor(v, 2, 64);
      v += __shfl_xor(v, 4, 64);
      v += __shfl_xor(v, 8, 64);
      pr[mt][r] = v;
    }
  if ((lane & 15) == 0) {
    #pragma unroll
    for (int mt = 0; mt < 2; ++mt)
      #pragma unroll
      for (int r = 0; r < 4; ++r)
        part[wave][mt * 16 + lg * 4 + r] = pr[mt][r];
  }
  __syncthreads();
  if (tid < 32)
    Zlog[b * T + t0 + tid] = part[0][tid] + part[1][tid] + part[2][tid] + part[3][tid] + W2_b[0];
}

// ---------------------------------------------------------------- K2: fact projections (MFMA f16, f16 out)
// Frh = f16(facts@Wr^T + Ur_b) ; Fgh = f16(facts@Wg^T)
__global__ __launch_bounds__(256, 2) void k_factproj(
    const float* __restrict__ facts, const f16* __restrict__ Wrh, const f16* __restrict__ Wgh,
    const float* __restrict__ Ur_b, f16* __restrict__ Frh, f16* __restrict__ Fgh)
{
  const int b = blockIdx.y;
  const int t0 = blockIdx.x * 64;
  const int tid = threadIdx.x;
  const int lane = tid & 63;
  const int wave = tid >> 6;
  const int lr = lane & 15;
  const int lg = lane >> 4;

  __shared__ __align__(16) char albuf[64 * 512];   // 64 rows x 256 f16, swizzled

  for (int c = tid; c < 64 * 32; c += 256) {
    int row = c >> 5;
    int kc = c & 31;
    const float* src = facts + ((int64_t)(b * T) + t0 + row) * D + kc * 8;
    float4 x0 = *(const float4*)src;
    float4 x1 = *(const float4*)(src + 4);
    f16x8 v;
    v[0] = (f16)x0.x; v[1] = (f16)x0.y; v[2] = (f16)x0.z; v[3] = (f16)x0.w;
    v[4] = (f16)x1.x; v[5] = (f16)x1.y; v[6] = (f16)x1.z; v[7] = (f16)x1.w;
    int byte = (row * 512 + kc * 16) ^ ((row & 7) << 4);
    *(f16x8*)(albuf + byte) = v;
  }
  __syncthreads();

  f32x4 accr[16], accg[16];
  #pragma unroll
  for (int i = 0; i < 16; ++i) { accr[i] = (f32x4){0.f,0.f,0.f,0.f}; accg[i] = (f32x4){0.f,0.f,0.f,0.f}; }

  const int arow = wave * 16 + lr;
  #pragma unroll 2
  for (int ks = 0; ks < 8; ++ks) {
    int byte = (arow * 512 + ks * 64 + lg * 16) ^ ((arow & 7) << 4);
    f16x8 af = *(const f16x8*)(albuf + byte);
    #pragma unroll
    for (int nt = 0; nt < 16; ++nt) {
      int a = nt * 16 + lr;
      f16x8 br = *(const f16x8*)(Wrh + a * 256 + ks * 32 + lg * 8);
      f16x8 bg = *(const f16x8*)(Wgh + a * 256 + ks * 32 + lg * 8);
      accr[nt] = __builtin_amdgcn_mfma_f32_16x16x32_f16(af, br, accr[nt], 0, 0, 0);
      accg[nt] = __builtin_amdgcn_mfma_f32_16x16x32_f16(af, bg, accg[nt], 0, 0, 0);
    }
  }

  #pragma unroll
  for (int nt = 0; nt < 16; ++nt) {
    int col = nt * 16 + lr;
    float urb = Ur_b[col];
    #pragma unroll
    for (int r = 0; r < 4; ++r) {
      int t = t0 + wave * 16 + lg * 4 + r;
      int64_t off = ((int64_t)(b * T) + t) * D + col;
      Frh[off] = (f16)(accr[nt][r] + urb);
      Fgh[off] = (f16)(accg[nt][r]);
    }
  }
}

// ---------------------------------------------------------------- K3: fused softmax + AGRU scan + final
// 64 blocks (1 batch each), 512 threads (8 waves).
// Thread: kg = lane&7 (k-slice of 32), rg = wave*8 + (lane>>3) (4 rows rg*4..+3).
// Weights: 4 rows x 32 k x 2 gates = 128 f16x2 VGPRs. h in bank-padded LDS
// chunks (8 x 80B), read 64B/thread/step -> 32 KB/block/step (4x less than v3).
// Reduce over the 8 kg lanes via shfl_xor(1,2,4).
__global__ __launch_bounds__(512) void k_scan_v5(
    const float* __restrict__ Zlog, const int* __restrict__ num_facts,
    const f16* __restrict__ Frh, const f16* __restrict__ Fgh,
    const float* __restrict__ Ur_w, const float* __restrict__ Ug_w,
    const float* __restrict__ Ug_b, const float* __restrict__ m_old,
    const float* __restrict__ queries, const float* __restrict__ Wt_w,
    const float* __restrict__ Wt_b, float* __restrict__ out)
{
  const int b = blockIdx.x;
  const int tid = threadIdx.x;
  const int l = tid & 63;
  const int w = tid >> 6;
  const int kg = l & 7;
  const int rg = w * 8 + (l >> 3);       // 0..63
  const int r0 = rg * 4;
  const int nf = num_facts[b];

  __shared__ __align__(16) char hbuf[2][640];      // 8 chunks x (64B data + 16B pad)
  __shared__ float g_lds[512];
  __shared__ float red[8];
  __shared__ __align__(16) float cat_s[768];

  // ---- fused masked softmax over this batch's 512 logits ----
  {
    float z = Zlog[b * 512 + tid];
    float v = (tid < nf) ? z : -INFINITY;
    float mx = v;
    #pragma unroll
    for (int s = 1; s < 64; s <<= 1) mx = fmaxf(mx, __shfl_xor(mx, s, 64));
    if (l == 0) red[w] = mx;
    __syncthreads();
    mx = red[0];
    #pragma unroll
    for (int j = 1; j < 8; ++j) mx = fmaxf(mx, red[j]);
    float e = (tid < nf) ? __expf(v - mx) : 0.f;
    float sum = e;
    #pragma unroll
    for (int s = 1; s < 64; s <<= 1) sum += __shfl_xor(sum, s, 64);
    __syncthreads();
    if (l == 0) red[w] = sum;
    __syncthreads();
    sum = red[0] + red[1] + red[2] + red[3] + red[4] + red[5] + red[6] + red[7];
    g_lds[tid] = e / sum;
  }

  // ---- weights into VGPRs: 4 rows x 16 f16x2 per gate ----
  f16x2 wR[4][16], wG[4][16];
  #pragma unroll
  for (int j = 0; j < 4; ++j) {
    const float* ur = Ur_w + (int64_t)(r0 + j) * 256 + kg * 32;
    const float* ug = Ug_w + (int64_t)(r0 + j) * 256 + kg * 32;
    #pragma unroll
    for (int q = 0; q < 8; ++q) {
      float4 a = *(const float4*)(ur + q * 4);
      float4 c = *(const float4*)(ug + q * 4);
      f16x2 p0; p0[0] = (f16)a.x; p0[1] = (f16)a.y;
      f16x2 p1; p1[0] = (f16)a.z; p1[1] = (f16)a.w;
      f16x2 q0; q0[0] = (f16)c.x; q0[1] = (f16)c.y;
      f16x2 q1; q1[0] = (f16)c.z; q1[1] = (f16)c.w;
      wR[j][q * 2 + 0] = p0;
      wR[j][q * 2 + 1] = p1;
      wG[j][q * 2 + 0] = q0;
      wG[j][q * 2 + 1] = q1;
    }
  }

  // ---- state ----
  float4 h0 = *(const float4*)(m_old + (int64_t)b * 256 + r0);
  float h[4] = {h0.x, h0.y, h0.z, h0.w};
  float4 ub4 = *(const float4*)(Ug_b + r0);

  const int haddr = (r0 >> 5) * 80 + (r0 & 31) * 2;   // chunk-padded address of rows r0..r0+3
  if (kg == 0) {
    f16x4 p; p[0] = (f16)h[0]; p[1] = (f16)h[1]; p[2] = (f16)h[2]; p[3] = (f16)h[3];
    *(f16x4*)(&hbuf[0][haddr]) = p;
  }

  const f16* __restrict__ frp = Frh + (int64_t)(b * T) * D + r0;
  const f16* __restrict__ fgp = Fgh + (int64_t)(b * T) * D + r0;
  f16x4 frv = *(const f16x4*)frp;
  f16x4 fgv = *(const f16x4*)fgp;

  __syncthreads();

  for (int t = 0; t < nf; ++t) {
    // h slice for this kg (32 f16, conflict-free: chunks hit disjoint bank sets)
    const char* hb = hbuf[t & 1];
    u32x4 hv0 = *(const u32x4*)(hb + kg * 80);
    u32x4 hv1 = *(const u32x4*)(hb + kg * 80 + 16);
    u32x4 hv2 = *(const u32x4*)(hb + kg * 80 + 32);
    u32x4 hv3 = *(const u32x4*)(hb + kg * 80 + 48);

    // prefetch next step's inputs
    f16x4 nfr = {}, nfg = {};
    if (t + 1 < nf) {
      nfr = *(const f16x4*)(frp + (int64_t)(t + 1) * D);
      nfg = *(const f16x4*)(fgp + (int64_t)(t + 1) * D);
    }
    float gt = g_lds[t];

    unsigned hu[16] = {hv0.x, hv0.y, hv0.z, hv0.w, hv1.x, hv1.y, hv1.z, hv1.w,
                       hv2.x, hv2.y, hv2.z, hv2.w, hv3.x, hv3.y, hv3.z, hv3.w};
    float aR[4] = {0.f, 0.f, 0.f, 0.f};
    float aG[4] = {0.f, 0.f, 0.f, 0.f};
    #pragma unroll
    for (int i2 = 0; i2 < 16; ++i2) {
      f16x2 hh = as_h2(hu[i2]);
      #pragma unroll
      for (int j = 0; j < 4; ++j) {
        aR[j] = dot2f(hh, wR[j][i2], aR[j]);
        aG[j] = dot2f(hh, wG[j][i2], aG[j]);
      }
    }
    // reduce over the 8 kg lanes (xor-butterfly: all lanes get the total)
    #pragma unroll
    for (int s = 1; s < 8; s <<= 1) {
      #pragma unroll
      for (int j = 0; j < 4; ++j) {
        aR[j] += __shfl_xor(aR[j], s, 64);
        aG[j] += __shfl_xor(aG[j], s, 64);
      }
    }

    // nonlinear + blend (all lanes compute redundantly; uniform, no divergence)
    f16x4 hp;
    #pragma unroll
    for (int j = 0; j < 4; ++j) {
      float fr = (float)frv[j];
      float fg = (float)fgv[j];
      float rr = __builtin_amdgcn_rcpf(1.f + __expf(-(fr + aR[j])));   // Ur_b folded in Fr
      float y  = fg + rr * (aG[j] + ub4[j == 0 ? 0 : j]);
      float ht = 1.f - 2.f * __builtin_amdgcn_rcpf(1.f + __expf(2.f * y));
      h[j] = h[j] + gt * (ht - h[j]);
      hp[j] = (f16)h[j];
    }
    if (kg == 0)
      *(f16x4*)(&hbuf[(t + 1) & 1][haddr]) = hp;

    frv = nfr;
    fgv = nfg;
    __syncthreads();
  }

  // ---- fused final: m_new = relu([m_old, c, q] @ Wt^T + bt) ----
  if (tid < 256) {
    cat_s[tid]       = m_old[(int64_t)b * 256 + tid];
    cat_s[512 + tid] = queries[(int64_t)b * 256 + tid];
  }
  if (kg == 0) {
    cat_s[256 + r0 + 0] = h[0];
    cat_s[256 + r0 + 1] = h[1];
    cat_s[256 + r0 + 2] = h[2];
    cat_s[256 + r0 + 3] = h[3];
  }
  __syncthreads();
  if (tid < 256) {
    const float* wrow = Wt_w + (int64_t)tid * 768;
    float acc = 0.f;
    #pragma unroll 8
    for (int k = 0; k < 768; k += 4) {
      float4 wv = *(const float4*)(wrow + k);
      float4 c4 = *(const float4*)(cat_s + k);
      acc += wv.x * c4.x + wv.y * c4.y + wv.z * c4.z + wv.w * c4.w;
    }
    out[(int64_t)b * 256 + tid] = fmaxf(acc + Wt_b[tid], 0.f);
  }
}

// ----------------------------------------------------------------
extern "C" void kernel_launch(void* const* d_in, const int* in_sizes, int n_in,
                              void* d_out, int out_size, void* d_ws, size_t ws_size,
                              hipStream_t stream)
{
  const float* queries   = (const float*)d_in[0];
  const float* facts     = (const float*)d_in[1];
  const int*   num_facts = (const int*)d_in[2];
  const float* m_old     = (const float*)d_in[3];
  const float* W1_w = (const float*)d_in[4];
  const float* W1_b = (const float*)d_in[5];
  const float* W2_w = (const float*)d_in[6];
  const float* W2_b = (const float*)d_in[7];
  const float* Wr_w = (const float*)d_in[8];
  const float* Ur_w = (const float*)d_in[9];
  const float* Ur_b = (const float*)d_in[10];
  const float* Wg_w = (const float*)d_in[11];
  const float* Ug_w = (const float*)d_in[12];
  const float* Ug_b = (const float*)d_in[13];
  const float* Wt_w = (const float*)d_in[14];
  const float* Wt_b = (const float*)d_in[15];
  float* out = (float*)d_out;

  char* p = (char*)d_ws;
  auto alloc = [&](size_t bytes) { char* r = p; p += (bytes + 255) & ~(size_t)255; return r; };
  f16*   W1h  = (f16*)alloc((size_t)256 * 1024 * 2);
  f16*   Wrh  = (f16*)alloc((size_t)65536 * 2);
  f16*   Wgh  = (f16*)alloc((size_t)65536 * 2);
  float* Zlog = (float*)alloc((size_t)B * T * 4);
  f16*   Frh  = (f16*)alloc((size_t)B * T * D * 2);
  f16*   Fgh  = (f16*)alloc((size_t)B * T * D * 2);

  k_convert<<<dim3(768), dim3(256), 0, stream>>>(W1_w, Wr_w, Wg_w, W1h, Wrh, Wgh);
  k_attn<<<dim3(16, 64), dim3(256), 0, stream>>>(facts, queries, m_old, W1h, W1_b, W2_w, W2_b, Zlog);
  k_factproj<<<dim3(8, 64), dim3(256), 0, stream>>>(facts, Wrh, Wgh, Ur_b, Frh, Fgh);
  k_scan_v5<<<dim3(64), dim3(512), 0, stream>>>(Zlog, num_facts, Frh, Fgh, Ur_w, Ug_w, Ug_b,
                                                m_old, queries, Wt_w, Wt_b, out);
}

// Round 8
// 811.073 us; speedup vs baseline: 1.1133x; 1.0895x over previous
//
#include <hip/hip_runtime.h>
#include <hip/hip_fp16.h>
#include <stdint.h>

#define B 64
#define T 512
#define D 256

typedef _Float16 f16;
typedef __attribute__((ext_vector_type(8))) _Float16 f16x8;
typedef __attribute__((ext_vector_type(4))) _Float16 f16x4;
typedef __attribute__((ext_vector_type(2))) _Float16 f16x2;
typedef __attribute__((ext_vector_type(4))) float f32x4;
typedef __attribute__((ext_vector_type(4))) unsigned int u32x4;

static __device__ __forceinline__ float dot2f(f16x2 a, f16x2 b, float c) {
  return __builtin_amdgcn_fdot2(a, b, c, false);
}
static __device__ __forceinline__ f16x2 as_h2(unsigned int u) {
  return __builtin_bit_cast(f16x2, u);
}

// ---------------------------------------------------------------- K0: weight f32->f16 converts
__global__ void k_convert(const float* __restrict__ W1, const float* __restrict__ Wr,
                          const float* __restrict__ Wg,
                          f16* __restrict__ W1h, f16* __restrict__ Wrh, f16* __restrict__ Wgh)
{
  const int64_t n1 = 256 * 1024, n2 = 65536, n3 = 65536;
  int64_t stride = (int64_t)gridDim.x * blockDim.x;
  for (int64_t i = (int64_t)blockIdx.x * blockDim.x + threadIdx.x; i < n1 + n2 + n3; i += stride) {
    if (i < n1)           W1h[i] = (f16)W1[i];
    else if (i < n1 + n2) Wrh[i - n1] = (f16)Wr[i - n1];
    else                  Wgh[i - n1 - n2] = (f16)Wg[i - n1 - n2];
  }
}

// ---------------------------------------------------------------- K1: attention logits (MFMA f16)
__global__ __launch_bounds__(256, 2) void k_attn(
    const float* __restrict__ facts, const float* __restrict__ queries,
    const float* __restrict__ m_old, const f16* __restrict__ W1h,
    const float* __restrict__ W1_b, const float* __restrict__ W2_w,
    const float* __restrict__ W2_b, float* __restrict__ Zlog)
{
  const int b = blockIdx.y;
  const int t0 = blockIdx.x * 32;
  const int tid = threadIdx.x;
  const int lane = tid & 63;
  const int wave = tid >> 6;
  const int lr = lane & 15;
  const int lg = lane >> 4;

  __shared__ float q_s[D], m_s[D];
  __shared__ __align__(16) char zbuf[32 * 2048];   // 32 rows x 1024 f16 (XOR-swizzled)
  __shared__ float part[4][32];

  q_s[tid] = queries[b * D + tid];
  m_s[tid] = m_old[b * D + tid];
  __syncthreads();

  for (int e = tid; e < 32 * 128; e += 256) {
    int t = e >> 7;
    int j2 = e & 127;
    int j = j2 * 2;
    const float2 f2 = *(const float2*)(facts + ((int64_t)(b * T) + t0 + t) * D + j);
    float q0 = q_s[j], q1 = q_s[j + 1], mm0 = m_s[j], mm1 = m_s[j + 1];
    f16x2 z0; z0[0] = (f16)(f2.x * q0);        z0[1] = (f16)(f2.y * q1);
    f16x2 z1; z1[0] = (f16)(f2.x * mm0);       z1[1] = (f16)(f2.y * mm1);
    f16x2 z2; z2[0] = (f16)fabsf(f2.x - q0);   z2[1] = (f16)fabsf(f2.y - q1);
    f16x2 z3; z3[0] = (f16)fabsf(f2.x - mm0);  z3[1] = (f16)fabsf(f2.y - mm1);
    int xr = (t & 7) << 4;
    int base = t * 2048;
    *(f16x2*)(zbuf + ((base + (0 * 128 + j2) * 4) ^ xr)) = z0;
    *(f16x2*)(zbuf + ((base + (1 * 128 + j2) * 4) ^ xr)) = z1;
    *(f16x2*)(zbuf + ((base + (2 * 128 + j2) * 4) ^ xr)) = z2;
    *(f16x2*)(zbuf + ((base + (3 * 128 + j2) * 4) ^ xr)) = z3;
  }
  __syncthreads();

  const int n0 = wave * 64;
  f32x4 acc[2][4];
  #pragma unroll
  for (int i = 0; i < 2; ++i)
    #pragma unroll
    for (int j = 0; j < 4; ++j) acc[i][j] = (f32x4){0.f, 0.f, 0.f, 0.f};

  #pragma unroll 2
  for (int ks = 0; ks < 32; ++ks) {
    f16x8 af[2];
    #pragma unroll
    for (int mt = 0; mt < 2; ++mt) {
      int row = mt * 16 + lr;
      int byte = (row * 2048 + ks * 64 + lg * 16) ^ ((row & 7) << 4);
      af[mt] = *(const f16x8*)(zbuf + byte);
    }
    #pragma unroll
    for (int nt = 0; nt < 4; ++nt) {
      int a = n0 + nt * 16 + lr;
      f16x8 bf = *(const f16x8*)(W1h + (int64_t)a * 1024 + ks * 32 + lg * 8);
      acc[0][nt] = __builtin_amdgcn_mfma_f32_16x16x32_f16(af[0], bf, acc[0][nt], 0, 0, 0);
      acc[1][nt] = __builtin_amdgcn_mfma_f32_16x16x32_f16(af[1], bf, acc[1][nt], 0, 0, 0);
    }
  }

  float pr[2][4] = {{0.f, 0.f, 0.f, 0.f}, {0.f, 0.f, 0.f, 0.f}};
  #pragma unroll
  for (int nt = 0; nt < 4; ++nt) {
    int a = n0 + nt * 16 + lr;
    float b1 = W1_b[a];
    float w2 = W2_w[a];
    #pragma unroll
    for (int mt = 0; mt < 2; ++mt)
      #pragma unroll
      for (int r = 0; r < 4; ++r)
        pr[mt][r] += tanhf(acc[mt][nt][r] + b1) * w2;
  }
  #pragma unroll
  for (int mt = 0; mt < 2; ++mt)
    #pragma unroll
    for (int r = 0; r < 4; ++r) {
      float v = pr[mt][r];
      v += __shfl_xor(v, 1, 64);
      v += __shfl_xor(v, 2, 64);
      v += __shfl_xor(v, 4, 64);
      v += __shfl_xor(v, 8, 64);
      pr[mt][r] = v;
    }
  if ((lane & 15) == 0) {
    #pragma unroll
    for (int mt = 0; mt < 2; ++mt)
      #pragma unroll
      for (int r = 0; r < 4; ++r)
        part[wave][mt * 16 + lg * 4 + r] = pr[mt][r];
  }
  __syncthreads();
  if (tid < 32)
    Zlog[b * T + t0 + tid] = part[0][tid] + part[1][tid] + part[2][tid] + part[3][tid] + W2_b[0];
}

// ---------------------------------------------------------------- K2: fact projections (MFMA f16, f16 out)
__global__ __launch_bounds__(256, 2) void k_factproj(
    const float* __restrict__ facts, const f16* __restrict__ Wrh, const f16* __restrict__ Wgh,
    const float* __restrict__ Ur_b, f16* __restrict__ Frh, f16* __restrict__ Fgh)
{
  const int b = blockIdx.y;
  const int t0 = blockIdx.x * 64;
  const int tid = threadIdx.x;
  const int lane = tid & 63;
  const int wave = tid >> 6;
  const int lr = lane & 15;
  const int lg = lane >> 4;

  __shared__ __align__(16) char albuf[64 * 512];   // 64 rows x 256 f16, swizzled

  for (int c = tid; c < 64 * 32; c += 256) {
    int row = c >> 5;
    int kc = c & 31;
    const float* src = facts + ((int64_t)(b * T) + t0 + row) * D + kc * 8;
    float4 x0 = *(const float4*)src;
    float4 x1 = *(const float4*)(src + 4);
    f16x8 v;
    v[0] = (f16)x0.x; v[1] = (f16)x0.y; v[2] = (f16)x0.z; v[3] = (f16)x0.w;
    v[4] = (f16)x1.x; v[5] = (f16)x1.y; v[6] = (f16)x1.z; v[7] = (f16)x1.w;
    int byte = (row * 512 + kc * 16) ^ ((row & 7) << 4);
    *(f16x8*)(albuf + byte) = v;
  }
  __syncthreads();

  f32x4 accr[16], accg[16];
  #pragma unroll
  for (int i = 0; i < 16; ++i) { accr[i] = (f32x4){0.f,0.f,0.f,0.f}; accg[i] = (f32x4){0.f,0.f,0.f,0.f}; }

  const int arow = wave * 16 + lr;
  #pragma unroll 2
  for (int ks = 0; ks < 8; ++ks) {
    int byte = (arow * 512 + ks * 64 + lg * 16) ^ ((arow & 7) << 4);
    f16x8 af = *(const f16x8*)(albuf + byte);
    #pragma unroll
    for (int nt = 0; nt < 16; ++nt) {
      int a = nt * 16 + lr;
      f16x8 br = *(const f16x8*)(Wrh + a * 256 + ks * 32 + lg * 8);
      f16x8 bg = *(const f16x8*)(Wgh + a * 256 + ks * 32 + lg * 8);
      accr[nt] = __builtin_amdgcn_mfma_f32_16x16x32_f16(af, br, accr[nt], 0, 0, 0);
      accg[nt] = __builtin_amdgcn_mfma_f32_16x16x32_f16(af, bg, accg[nt], 0, 0, 0);
    }
  }

  #pragma unroll
  for (int nt = 0; nt < 16; ++nt) {
    int col = nt * 16 + lr;
    float urb = Ur_b[col];
    #pragma unroll
    for (int r = 0; r < 4; ++r) {
      int t = t0 + wave * 16 + lg * 4 + r;
      int64_t off = ((int64_t)(b * T) + t) * D + col;
      Frh[off] = (f16)(accr[nt][r] + urb);
      Fgh[off] = (f16)(accg[nt][r]);
    }
  }
}

// ---------------------------------------------------------------- K3: fused softmax + AGRU scan + final
// 64 blocks (1 batch), 256 threads (4 waves, 1/SIMD).
// Thread: q = lane>>5 (k-half), p = wave*32 + (lane&31) in 0..127 -> rows 2p, 2p+1.
// Weights: 2 rows x 2 gates x 64 f16x2 = 256 VGPRs. Per step: 16 ds_read_b128
// (broadcast within q-group), 4 shfl_xor(32), 1 ds_write_b32, 1 barrier.
__global__ __launch_bounds__(256, 1) void k_scan_v6(
    const float* __restrict__ Zlog, const int* __restrict__ num_facts,
    const f16* __restrict__ Frh, const f16* __restrict__ Fgh,
    const float* __restrict__ Ur_w, const float* __restrict__ Ug_w,
    const float* __restrict__ Ug_b, const float* __restrict__ m_old,
    const float* __restrict__ queries, const float* __restrict__ Wt_w,
    const float* __restrict__ Wt_b, float* __restrict__ out)
{
  const int b = blockIdx.x;
  const int tid = threadIdx.x;
  const int lane = tid & 63;
  const int w = tid >> 6;
  const int q = lane >> 5;
  const int p = w * 32 + (lane & 31);    // 0..127; rows 2p, 2p+1
  const int nf = num_facts[b];

  __shared__ __align__(16) char hbuf[2][544];   // two 256B k-halves + 16B pad between
  __shared__ float g_lds[512];
  __shared__ float redM[4], redS[4];
  __shared__ __align__(16) float cat_s[768];

  // ---- fused masked softmax (each thread: logits tid, tid+256) ----
  {
    float z0 = Zlog[b * 512 + tid];
    float z1 = Zlog[b * 512 + 256 + tid];
    float v0 = (tid < nf) ? z0 : -INFINITY;
    float v1 = (tid + 256 < nf) ? z1 : -INFINITY;
    float mx = fmaxf(v0, v1);
    #pragma unroll
    for (int s = 1; s < 64; s <<= 1) mx = fmaxf(mx, __shfl_xor(mx, s, 64));
    if (lane == 0) redM[w] = mx;
    __syncthreads();
    mx = fmaxf(fmaxf(redM[0], redM[1]), fmaxf(redM[2], redM[3]));
    float e0 = (tid < nf) ? __expf(v0 - mx) : 0.f;
    float e1 = (tid + 256 < nf) ? __expf(v1 - mx) : 0.f;
    float sum = e0 + e1;
    #pragma unroll
    for (int s = 1; s < 64; s <<= 1) sum += __shfl_xor(sum, s, 64);
    if (lane == 0) redS[w] = sum;
    __syncthreads();
    float inv = 1.f / (redS[0] + redS[1] + redS[2] + redS[3]);
    g_lds[tid] = e0 * inv;
    g_lds[256 + tid] = e1 * inv;
  }

  // ---- weights into VGPRs: rows 2p+j, k-half q, both gates ----
  f16x2 wR[2][64], wG[2][64];
  #pragma unroll
  for (int j = 0; j < 2; ++j) {
    const float* ur = Ur_w + (int64_t)(2 * p + j) * 256 + q * 128;
    const float* ug = Ug_w + (int64_t)(2 * p + j) * 256 + q * 128;
    #pragma unroll
    for (int c = 0; c < 32; ++c) {
      float4 a = *(const float4*)(ur + c * 4);
      float4 g4 = *(const float4*)(ug + c * 4);
      f16x2 p0; p0[0] = (f16)a.x;  p0[1] = (f16)a.y;
      f16x2 p1; p1[0] = (f16)a.z;  p1[1] = (f16)a.w;
      f16x2 q0; q0[0] = (f16)g4.x; q0[1] = (f16)g4.y;
      f16x2 q1; q1[0] = (f16)g4.z; q1[1] = (f16)g4.w;
      wR[j][c * 2 + 0] = p0;
      wR[j][c * 2 + 1] = p1;
      wG[j][c * 2 + 0] = q0;
      wG[j][c * 2 + 1] = q1;
    }
  }

  // ---- state: h rows 2p, 2p+1 ----
  float2 h2 = *(const float2*)(m_old + (int64_t)b * 256 + 2 * p);
  float h0 = h2.x, h1 = h2.y;
  float2 ub2 = *(const float2*)(Ug_b + 2 * p);

  const int waddr = 4 * p + (p >= 64 ? 16 : 0);   // byte addr of rows 2p,2p+1 (f16x2)
  if (q == 0) {
    f16x2 hp; hp[0] = (f16)h0; hp[1] = (f16)h1;
    *(f16x2*)(&hbuf[0][waddr]) = hp;
  }

  const f16* __restrict__ frp = Frh + (int64_t)(b * T) * D + 2 * p;
  const f16* __restrict__ fgp = Fgh + (int64_t)(b * T) * D + 2 * p;
  f16x2 frv = *(const f16x2*)frp;
  f16x2 fgv = *(const f16x2*)fgp;

  __syncthreads();

  for (int t = 0; t < nf; ++t) {
    const char* hb = hbuf[t & 1] + q * 272;
    u32x4 hv[4];
    #pragma unroll
    for (int c = 0; c < 4; ++c) hv[c] = *(const u32x4*)(hb + c * 16);
    u32x4 hw[4];
    #pragma unroll
    for (int c = 0; c < 4; ++c) hw[c] = *(const u32x4*)(hb + 64 + c * 16);
    u32x4 hx[4];
    #pragma unroll
    for (int c = 0; c < 4; ++c) hx[c] = *(const u32x4*)(hb + 128 + c * 16);
    u32x4 hy[4];
    #pragma unroll
    for (int c = 0; c < 4; ++c) hy[c] = *(const u32x4*)(hb + 192 + c * 16);

    f16x2 nfr = {}, nfg = {};
    if (t + 1 < nf) {
      nfr = *(const f16x2*)(frp + (int64_t)(t + 1) * D);
      nfg = *(const f16x2*)(fgp + (int64_t)(t + 1) * D);
    }
    float gt = g_lds[t];

    // 8 accumulator chains (2 per output value), 32 deep each
    float aR0a = 0.f, aR0b = 0.f, aR1a = 0.f, aR1b = 0.f;
    float aG0a = 0.f, aG0b = 0.f, aG1a = 0.f, aG1b = 0.f;
    unsigned hu[64];
    #pragma unroll
    for (int c = 0; c < 4; ++c) {
      hu[c * 4 + 0]  = hv[c].x; hu[c * 4 + 1]  = hv[c].y; hu[c * 4 + 2]  = hv[c].z; hu[c * 4 + 3]  = hv[c].w;
      hu[16 + c * 4 + 0] = hw[c].x; hu[16 + c * 4 + 1] = hw[c].y; hu[16 + c * 4 + 2] = hw[c].z; hu[16 + c * 4 + 3] = hw[c].w;
      hu[32 + c * 4 + 0] = hx[c].x; hu[32 + c * 4 + 1] = hx[c].y; hu[32 + c * 4 + 2] = hx[c].z; hu[32 + c * 4 + 3] = hx[c].w;
      hu[48 + c * 4 + 0] = hy[c].x; hu[48 + c * 4 + 1] = hy[c].y; hu[48 + c * 4 + 2] = hy[c].z; hu[48 + c * 4 + 3] = hy[c].w;
    }
    #pragma unroll
    for (int i2 = 0; i2 < 32; ++i2) {
      f16x2 ha = as_h2(hu[i2 * 2]);
      f16x2 hbv = as_h2(hu[i2 * 2 + 1]);
      aR0a = dot2f(ha, wR[0][i2 * 2], aR0a);
      aR0b = dot2f(hbv, wR[0][i2 * 2 + 1], aR0b);
      aR1a = dot2f(ha, wR[1][i2 * 2], aR1a);
      aR1b = dot2f(hbv, wR[1][i2 * 2 + 1], aR1b);
      aG0a = dot2f(ha, wG[0][i2 * 2], aG0a);
      aG0b = dot2f(hbv, wG[0][i2 * 2 + 1], aG0b);
      aG1a = dot2f(ha, wG[1][i2 * 2], aG1a);
      aG1b = dot2f(hbv, wG[1][i2 * 2 + 1], aG1b);
    }
    float aR0 = aR0a + aR0b, aR1 = aR1a + aR1b;
    float aG0 = aG0a + aG0b, aG1 = aG1a + aG1b;
    aR0 += __shfl_xor(aR0, 32, 64);
    aR1 += __shfl_xor(aR1, 32, 64);
    aG0 += __shfl_xor(aG0, 32, 64);
    aG1 += __shfl_xor(aG1, 32, 64);

    // nonlinear + blend (both q compute redundantly; uniform)
    {
      float fr0 = (float)frv[0], fr1 = (float)frv[1];
      float fg0 = (float)fgv[0], fg1 = (float)fgv[1];
      float rr0 = __builtin_amdgcn_rcpf(1.f + __expf(-(fr0 + aR0)));
      float rr1 = __builtin_amdgcn_rcpf(1.f + __expf(-(fr1 + aR1)));
      float y0 = fg0 + rr0 * (aG0 + ub2.x);
      float y1 = fg1 + rr1 * (aG1 + ub2.y);
      float ht0 = 1.f - 2.f * __builtin_amdgcn_rcpf(1.f + __expf(2.f * y0));
      float ht1 = 1.f - 2.f * __builtin_amdgcn_rcpf(1.f + __expf(2.f * y1));
      h0 = h0 + gt * (ht0 - h0);
      h1 = h1 + gt * (ht1 - h1);
    }
    if (q == 0) {
      f16x2 hp; hp[0] = (f16)h0; hp[1] = (f16)h1;
      *(f16x2*)(&hbuf[(t + 1) & 1][waddr]) = hp;
    }
    frv = nfr;
    fgv = nfg;
    __syncthreads();
  }

  // ---- fused final: m_new = relu([m_old, c, q] @ Wt^T + bt) ----
  cat_s[tid]       = m_old[(int64_t)b * 256 + tid];
  cat_s[512 + tid] = queries[(int64_t)b * 256 + tid];
  if (q == 0) {
    cat_s[256 + 2 * p]     = h0;
    cat_s[256 + 2 * p + 1] = h1;
  }
  __syncthreads();
  {
    const float* wrow = Wt_w + (int64_t)tid * 768;
    float acc = 0.f;
    #pragma unroll 8
    for (int k = 0; k < 768; k += 4) {
      float4 wv = *(const float4*)(wrow + k);
      float4 c4 = *(const float4*)(cat_s + k);
      acc += wv.x * c4.x + wv.y * c4.y + wv.z * c4.z + wv.w * c4.w;
    }
    out[(int64_t)b * 256 + tid] = fmaxf(acc + Wt_b[tid], 0.f);
  }
}

// ----------------------------------------------------------------
extern "C" void kernel_launch(void* const* d_in, const int* in_sizes, int n_in,
                              void* d_out, int out_size, void* d_ws, size_t ws_size,
                              hipStream_t stream)
{
  const float* queries   = (const float*)d_in[0];
  const float* facts     = (const float*)d_in[1];
  const int*   num_facts = (const int*)d_in[2];
  const float* m_old     = (const float*)d_in[3];
  const float* W1_w = (const float*)d_in[4];
  const float* W1_b = (const float*)d_in[5];
  const float* W2_w = (const float*)d_in[6];
  const float* W2_b = (const float*)d_in[7];
  const float* Wr_w = (const float*)d_in[8];
  const float* Ur_w = (const float*)d_in[9];
  const float* Ur_b = (const float*)d_in[10];
  const float* Wg_w = (const float*)d_in[11];
  const float* Ug_w = (const float*)d_in[12];
  const float* Ug_b = (const float*)d_in[13];
  const float* Wt_w = (const float*)d_in[14];
  const float* Wt_b = (const float*)d_in[15];
  float* out = (float*)d_out;

  char* p = (char*)d_ws;
  auto alloc = [&](size_t bytes) { char* r = p; p += (bytes + 255) & ~(size_t)255; return r; };
  f16*   W1h  = (f16*)alloc((size_t)256 * 1024 * 2);
  f16*   Wrh  = (f16*)alloc((size_t)65536 * 2);
  f16*   Wgh  = (f16*)alloc((size_t)65536 * 2);
  float* Zlog = (float*)alloc((size_t)B * T * 4);
  f16*   Frh  = (f16*)alloc((size_t)B * T * D * 2);
  f16*   Fgh  = (f16*)alloc((size_t)B * T * D * 2);

  k_convert<<<dim3(768), dim3(256), 0, stream>>>(W1_w, Wr_w, Wg_w, W1h, Wrh, Wgh);
  k_attn<<<dim3(16, 64), dim3(256), 0, stream>>>(facts, queries, m_old, W1h, W1_b, W2_w, W2_b, Zlog);
  k_factproj<<<dim3(8, 64), dim3(256), 0, stream>>>(facts, Wrh, Wgh, Ur_b, Frh, Fgh);
  k_scan_v6<<<dim3(64), dim3(256), 0, stream>>>(Zlog, num_facts, Frh, Fgh, Ur_w, Ug_w, Ug_b,
                                                m_old, queries, Wt_w, Wt_b, out);
}

// Round 9
// 709.181 us; speedup vs baseline: 1.2732x; 1.1437x over previous
//
#include <hip/hip_runtime.h>
#include <hip/hip_fp16.h>
#include <stdint.h>

#define B 64
#define T 512
#define D 256

typedef _Float16 f16;
typedef __attribute__((ext_vector_type(8))) _Float16 f16x8;
typedef __attribute__((ext_vector_type(4))) _Float16 f16x4;
typedef __attribute__((ext_vector_type(2))) _Float16 f16x2;
typedef __attribute__((ext_vector_type(4))) float f32x4;
typedef __attribute__((ext_vector_type(4))) unsigned int u32x4;

static __device__ __forceinline__ float dot2f(f16x2 a, f16x2 b, float c) {
  return __builtin_amdgcn_fdot2(a, b, c, false);
}
static __device__ __forceinline__ f16x2 as_h2(unsigned int u) {
  return __builtin_bit_cast(f16x2, u);
}
// quad_perm DPP adds (VALU pipe — no DS): xor1 = [1,0,3,2] = 0xB1, xor2 = [2,3,0,1] = 0x4E
static __device__ __forceinline__ float dpp_add_xor1(float x) {
  int s = __builtin_amdgcn_update_dpp(0, __builtin_bit_cast(int, x), 0xB1, 0xf, 0xf, true);
  return x + __builtin_bit_cast(float, s);
}
static __device__ __forceinline__ float dpp_add_xor2(float x) {
  int s = __builtin_amdgcn_update_dpp(0, __builtin_bit_cast(int, x), 0x4E, 0xf, 0xf, true);
  return x + __builtin_bit_cast(float, s);
}

// ---------------------------------------------------------------- K0: weight f32->f16 converts
__global__ void k_convert(const float* __restrict__ W1, const float* __restrict__ Wr,
                          const float* __restrict__ Wg,
                          f16* __restrict__ W1h, f16* __restrict__ Wrh, f16* __restrict__ Wgh)
{
  const int64_t n1 = 256 * 1024, n2 = 65536, n3 = 65536;
  int64_t stride = (int64_t)gridDim.x * blockDim.x;
  for (int64_t i = (int64_t)blockIdx.x * blockDim.x + threadIdx.x; i < n1 + n2 + n3; i += stride) {
    if (i < n1)           W1h[i] = (f16)W1[i];
    else if (i < n1 + n2) Wrh[i - n1] = (f16)Wr[i - n1];
    else                  Wgh[i - n1 - n2] = (f16)Wg[i - n1 - n2];
  }
}

// ---------------------------------------------------------------- K1: attention logits (MFMA f16)
__global__ __launch_bounds__(256, 2) void k_attn(
    const float* __restrict__ facts, const float* __restrict__ queries,
    const float* __restrict__ m_old, const f16* __restrict__ W1h,
    const float* __restrict__ W1_b, const float* __restrict__ W2_w,
    const float* __restrict__ W2_b, float* __restrict__ Zlog)
{
  const int b = blockIdx.y;
  const int t0 = blockIdx.x * 32;
  const int tid = threadIdx.x;
  const int lane = tid & 63;
  const int wave = tid >> 6;
  const int lr = lane & 15;
  const int lg = lane >> 4;

  __shared__ float q_s[D], m_s[D];
  __shared__ __align__(16) char zbuf[32 * 2048];   // 32 rows x 1024 f16 (XOR-swizzled)
  __shared__ float part[4][32];

  q_s[tid] = queries[b * D + tid];
  m_s[tid] = m_old[b * D + tid];
  __syncthreads();

  for (int e = tid; e < 32 * 128; e += 256) {
    int t = e >> 7;
    int j2 = e & 127;
    int j = j2 * 2;
    const float2 f2 = *(const float2*)(facts + ((int64_t)(b * T) + t0 + t) * D + j);
    float q0 = q_s[j], q1 = q_s[j + 1], mm0 = m_s[j], mm1 = m_s[j + 1];
    f16x2 z0; z0[0] = (f16)(f2.x * q0);        z0[1] = (f16)(f2.y * q1);
    f16x2 z1; z1[0] = (f16)(f2.x * mm0);       z1[1] = (f16)(f2.y * mm1);
    f16x2 z2; z2[0] = (f16)fabsf(f2.x - q0);   z2[1] = (f16)fabsf(f2.y - q1);
    f16x2 z3; z3[0] = (f16)fabsf(f2.x - mm0);  z3[1] = (f16)fabsf(f2.y - mm1);
    int xr = (t & 7) << 4;
    int base = t * 2048;
    *(f16x2*)(zbuf + ((base + (0 * 128 + j2) * 4) ^ xr)) = z0;
    *(f16x2*)(zbuf + ((base + (1 * 128 + j2) * 4) ^ xr)) = z1;
    *(f16x2*)(zbuf + ((base + (2 * 128 + j2) * 4) ^ xr)) = z2;
    *(f16x2*)(zbuf + ((base + (3 * 128 + j2) * 4) ^ xr)) = z3;
  }
  __syncthreads();

  const int n0 = wave * 64;
  f32x4 acc[2][4];
  #pragma unroll
  for (int i = 0; i < 2; ++i)
    #pragma unroll
    for (int j = 0; j < 4; ++j) acc[i][j] = (f32x4){0.f, 0.f, 0.f, 0.f};

  #pragma unroll 2
  for (int ks = 0; ks < 32; ++ks) {
    f16x8 af[2];
    #pragma unroll
    for (int mt = 0; mt < 2; ++mt) {
      int row = mt * 16 + lr;
      int byte = (row * 2048 + ks * 64 + lg * 16) ^ ((row & 7) << 4);
      af[mt] = *(const f16x8*)(zbuf + byte);
    }
    #pragma unroll
    for (int nt = 0; nt < 4; ++nt) {
      int a = n0 + nt * 16 + lr;
      f16x8 bf = *(const f16x8*)(W1h + (int64_t)a * 1024 + ks * 32 + lg * 8);
      acc[0][nt] = __builtin_amdgcn_mfma_f32_16x16x32_f16(af[0], bf, acc[0][nt], 0, 0, 0);
      acc[1][nt] = __builtin_amdgcn_mfma_f32_16x16x32_f16(af[1], bf, acc[1][nt], 0, 0, 0);
    }
  }

  float pr[2][4] = {{0.f, 0.f, 0.f, 0.f}, {0.f, 0.f, 0.f, 0.f}};
  #pragma unroll
  for (int nt = 0; nt < 4; ++nt) {
    int a = n0 + nt * 16 + lr;
    float b1 = W1_b[a];
    float w2 = W2_w[a];
    #pragma unroll
    for (int mt = 0; mt < 2; ++mt)
      #pragma unroll
      for (int r = 0; r < 4; ++r)
        pr[mt][r] += tanhf(acc[mt][nt][r] + b1) * w2;
  }
  #pragma unroll
  for (int mt = 0; mt < 2; ++mt)
    #pragma unroll
    for (int r = 0; r < 4; ++r) {
      float v = pr[mt][r];
      v += __shfl_xor(v, 1, 64);
      v += __shfl_xor(v, 2, 64);
      v += __shfl_xor(v, 4, 64);
      v += __shfl_xor(v, 8, 64);
      pr[mt][r] = v;
    }
  if ((lane & 15) == 0) {
    #pragma unroll
    for (int mt = 0; mt < 2; ++mt)
      #pragma unroll
      for (int r = 0; r < 4; ++r)
        part[wave][mt * 16 + lg * 4 + r] = pr[mt][r];
  }
  __syncthreads();
  if (tid < 32)
    Zlog[b * T + t0 + tid] = part[0][tid] + part[1][tid] + part[2][tid] + part[3][tid] + W2_b[0];
}

// ---------------------------------------------------------------- K2: fact projections (MFMA f16, f16 out)
__global__ __launch_bounds__(256, 2) void k_factproj(
    const float* __restrict__ facts, const f16* __restrict__ Wrh, const f16* __restrict__ Wgh,
    const float* __restrict__ Ur_b, f16* __restrict__ Frh, f16* __restrict__ Fgh)
{
  const int b = blockIdx.y;
  const int t0 = blockIdx.x * 64;
  const int tid = threadIdx.x;
  const int lane = tid & 63;
  const int wave = tid >> 6;
  const int lr = lane & 15;
  const int lg = lane >> 4;

  __shared__ __align__(16) char albuf[64 * 512];   // 64 rows x 256 f16, swizzled

  for (int c = tid; c < 64 * 32; c += 256) {
    int row = c >> 5;
    int kc = c & 31;
    const float* src = facts + ((int64_t)(b * T) + t0 + row) * D + kc * 8;
    float4 x0 = *(const float4*)src;
    float4 x1 = *(const float4*)(src + 4);
    f16x8 v;
    v[0] = (f16)x0.x; v[1] = (f16)x0.y; v[2] = (f16)x0.z; v[3] = (f16)x0.w;
    v[4] = (f16)x1.x; v[5] = (f16)x1.y; v[6] = (f16)x1.z; v[7] = (f16)x1.w;
    int byte = (row * 512 + kc * 16) ^ ((row & 7) << 4);
    *(f16x8*)(albuf + byte) = v;
  }
  __syncthreads();

  f32x4 accr[16], accg[16];
  #pragma unroll
  for (int i = 0; i < 16; ++i) { accr[i] = (f32x4){0.f,0.f,0.f,0.f}; accg[i] = (f32x4){0.f,0.f,0.f,0.f}; }

  const int arow = wave * 16 + lr;
  #pragma unroll 2
  for (int ks = 0; ks < 8; ++ks) {
    int byte = (arow * 512 + ks * 64 + lg * 16) ^ ((arow & 7) << 4);
    f16x8 af = *(const f16x8*)(albuf + byte);
    #pragma unroll
    for (int nt = 0; nt < 16; ++nt) {
      int a = nt * 16 + lr;
      f16x8 br = *(const f16x8*)(Wrh + a * 256 + ks * 32 + lg * 8);
      f16x8 bg = *(const f16x8*)(Wgh + a * 256 + ks * 32 + lg * 8);
      accr[nt] = __builtin_amdgcn_mfma_f32_16x16x32_f16(af, br, accr[nt], 0, 0, 0);
      accg[nt] = __builtin_amdgcn_mfma_f32_16x16x32_f16(af, bg, accg[nt], 0, 0, 0);
    }
  }

  #pragma unroll
  for (int nt = 0; nt < 16; ++nt) {
    int col = nt * 16 + lr;
    float urb = Ur_b[col];
    #pragma unroll
    for (int r = 0; r < 4; ++r) {
      int t = t0 + wave * 16 + lg * 4 + r;
      int64_t off = ((int64_t)(b * T) + t) * D + col;
      Frh[off] = (f16)(accr[nt][r] + urb);
      Fgh[off] = (f16)(accg[nt][r]);
    }
  }
}

// ---------------------------------------------------------------- K3: fused softmax + AGRU scan + final
// 64 blocks (1 batch), 512 threads (8 waves, 2/SIMD).
// Thread: kq = lane&3 (k-quarter, 64 f16), pi = wave*16 + (lane>>2) -> rows 2pi, 2pi+1.
// Weights: 2 rows x 2 gates x 32 f16x2 = 128 VGPRs (NO spill; v6 hit the 256 arch cap).
// k-quarter reduction = quad_perm DPP adds (VALU pipe, zero DS instructions).
// h quarters padded to 144B stride -> the 4 addresses per ds_read_b128 hit
// disjoint bank sets. Per block/step: 64 ds_read + 8 g-read + 8 ds_write.
__global__ __launch_bounds__(512, 1) void k_scan_v7(
    const float* __restrict__ Zlog, const int* __restrict__ num_facts,
    const f16* __restrict__ Frh, const f16* __restrict__ Fgh,
    const float* __restrict__ Ur_w, const float* __restrict__ Ug_w,
    const float* __restrict__ Ug_b, const float* __restrict__ m_old,
    const float* __restrict__ queries, const float* __restrict__ Wt_w,
    const float* __restrict__ Wt_b, float* __restrict__ out)
{
  const int b = blockIdx.x;
  const int tid = threadIdx.x;
  const int lane = tid & 63;
  const int w = tid >> 6;
  const int kq = lane & 3;
  const int pi = w * 16 + (lane >> 2);   // 0..127; rows 2pi, 2pi+1
  const int nf = num_facts[b];

  __shared__ __align__(16) char hbuf[2][576];   // 4 quarters x (128B data + 16B pad)
  __shared__ float g_lds[512];
  __shared__ float redM[8], redS[8];
  __shared__ __align__(16) float cat_s[768];

  // ---- fused masked softmax over this batch's 512 logits (1 logit/thread) ----
  {
    float z = Zlog[b * 512 + tid];
    float v = (tid < nf) ? z : -INFINITY;
    float mx = v;
    #pragma unroll
    for (int s = 1; s < 64; s <<= 1) mx = fmaxf(mx, __shfl_xor(mx, s, 64));
    if (lane == 0) redM[w] = mx;
    __syncthreads();
    mx = redM[0];
    #pragma unroll
    for (int j = 1; j < 8; ++j) mx = fmaxf(mx, redM[j]);
    float e = (tid < nf) ? __expf(v - mx) : 0.f;
    float sum = e;
    #pragma unroll
    for (int s = 1; s < 64; s <<= 1) sum += __shfl_xor(sum, s, 64);
    if (lane == 0) redS[w] = sum;
    __syncthreads();
    float inv = 1.f / (redS[0] + redS[1] + redS[2] + redS[3] +
                       redS[4] + redS[5] + redS[6] + redS[7]);
    g_lds[tid] = e * inv;
  }

  // ---- weights into VGPRs: rows 2pi+j, k-quarter kq, both gates (32 f16x2 each) ----
  f16x2 wR[2][32], wG[2][32];
  #pragma unroll
  for (int j = 0; j < 2; ++j) {
    const float* ur = Ur_w + (int64_t)(2 * pi + j) * 256 + kq * 64;
    const float* ug = Ug_w + (int64_t)(2 * pi + j) * 256 + kq * 64;
    #pragma unroll
    for (int c = 0; c < 16; ++c) {
      float4 a = *(const float4*)(ur + c * 4);
      float4 g4 = *(const float4*)(ug + c * 4);
      f16x2 p0; p0[0] = (f16)a.x;  p0[1] = (f16)a.y;
      f16x2 p1; p1[0] = (f16)a.z;  p1[1] = (f16)a.w;
      f16x2 q0; q0[0] = (f16)g4.x; q0[1] = (f16)g4.y;
      f16x2 q1; q1[0] = (f16)g4.z; q1[1] = (f16)g4.w;
      wR[j][c * 2 + 0] = p0;
      wR[j][c * 2 + 1] = p1;
      wG[j][c * 2 + 0] = q0;
      wG[j][c * 2 + 1] = q1;
    }
  }

  // ---- state: h rows 2pi, 2pi+1 ----
  float2 h2 = *(const float2*)(m_old + (int64_t)b * 256 + 2 * pi);
  float h0 = h2.x, h1 = h2.y;
  float2 ub2 = *(const float2*)(Ug_b + 2 * pi);

  // h LDS layout: quarter q at byte q*144; row r at (r & 63)*2 within it
  const int hwaddr = ((2 * pi) >> 6) * 144 + ((2 * pi) & 63) * 2;
  if (kq == 0) {
    f16x2 hp; hp[0] = (f16)h0; hp[1] = (f16)h1;
    *(f16x2*)(&hbuf[0][hwaddr]) = hp;
  }

  const f16* __restrict__ frp = Frh + (int64_t)(b * T) * D + 2 * pi;
  const f16* __restrict__ fgp = Fgh + (int64_t)(b * T) * D + 2 * pi;
  f16x2 frv = *(const f16x2*)frp;
  f16x2 fgv = *(const f16x2*)fgp;

  __syncthreads();

  for (int t = 0; t < nf; ++t) {
    // this thread's 64-f16 k-quarter of h (8 x b128; 4 distinct addrs/instr, disjoint banks)
    const char* hb = hbuf[t & 1] + kq * 144;
    u32x4 hv[8];
    #pragma unroll
    for (int c = 0; c < 8; ++c) hv[c] = *(const u32x4*)(hb + c * 16);

    float gt = g_lds[t];
    f16x2 nfr = {}, nfg = {};
    if (t + 1 < nf) {
      nfr = *(const f16x2*)(frp + (int64_t)(t + 1) * D);
      nfg = *(const f16x2*)(fgp + (int64_t)(t + 1) * D);
    }

    // 128 dot2 over the quarter: 4 row-gates x 2 chains x 16 deep
    float aR0a = 0.f, aR0b = 0.f, aR1a = 0.f, aR1b = 0.f;
    float aG0a = 0.f, aG0b = 0.f, aG1a = 0.f, aG1b = 0.f;
    #pragma unroll
    for (int c = 0; c < 8; ++c) {
      f16x2 x0 = as_h2(hv[c].x), x1 = as_h2(hv[c].y);
      f16x2 x2 = as_h2(hv[c].z), x3 = as_h2(hv[c].w);
      int i0 = c * 4;
      aR0a = dot2f(x0, wR[0][i0 + 0], aR0a);
      aR0b = dot2f(x1, wR[0][i0 + 1], aR0b);
      aR0a = dot2f(x2, wR[0][i0 + 2], aR0a);
      aR0b = dot2f(x3, wR[0][i0 + 3], aR0b);
      aR1a = dot2f(x0, wR[1][i0 + 0], aR1a);
      aR1b = dot2f(x1, wR[1][i0 + 1], aR1b);
      aR1a = dot2f(x2, wR[1][i0 + 2], aR1a);
      aR1b = dot2f(x3, wR[1][i0 + 3], aR1b);
      aG0a = dot2f(x0, wG[0][i0 + 0], aG0a);
      aG0b = dot2f(x1, wG[0][i0 + 1], aG0b);
      aG0a = dot2f(x2, wG[0][i0 + 2], aG0a);
      aG0b = dot2f(x3, wG[0][i0 + 3], aG0b);
      aG1a = dot2f(x0, wG[1][i0 + 0], aG1a);
      aG1b = dot2f(x1, wG[1][i0 + 1], aG1b);
      aG1a = dot2f(x2, wG[1][i0 + 2], aG1a);
      aG1b = dot2f(x3, wG[1][i0 + 3], aG1b);
    }
    float aR0 = aR0a + aR0b, aR1 = aR1a + aR1b;
    float aG0 = aG0a + aG0b, aG1 = aG1a + aG1b;
    // reduce across the 4 k-quarter lanes: quad_perm DPP (VALU), butterfly
    aR0 = dpp_add_xor2(dpp_add_xor1(aR0));
    aR1 = dpp_add_xor2(dpp_add_xor1(aR1));
    aG0 = dpp_add_xor2(dpp_add_xor1(aG0));
    aG1 = dpp_add_xor2(dpp_add_xor1(aG1));

    // nonlinear + blend (uniform across the 4 kq lanes)
    {
      float fr0 = (float)frv[0], fr1 = (float)frv[1];
      float fg0 = (float)fgv[0], fg1 = (float)fgv[1];
      float rr0 = __builtin_amdgcn_rcpf(1.f + __expf(-(fr0 + aR0)));   // Ur_b folded in Fr
      float rr1 = __builtin_amdgcn_rcpf(1.f + __expf(-(fr1 + aR1)));
      float y0 = fg0 + rr0 * (aG0 + ub2.x);
      float y1 = fg1 + rr1 * (aG1 + ub2.y);
      float ht0 = 1.f - 2.f * __builtin_amdgcn_rcpf(1.f + __expf(2.f * y0));
      float ht1 = 1.f - 2.f * __builtin_amdgcn_rcpf(1.f + __expf(2.f * y1));
      h0 = h0 + gt * (ht0 - h0);
      h1 = h1 + gt * (ht1 - h1);
    }
    if (kq == 0) {
      f16x2 hp; hp[0] = (f16)h0; hp[1] = (f16)h1;
      *(f16x2*)(&hbuf[(t + 1) & 1][hwaddr]) = hp;
    }
    frv = nfr;
    fgv = nfg;
    __syncthreads();
  }

  // ---- fused final: m_new = relu([m_old, c, q] @ Wt^T + bt) ----
  if (tid < 256) cat_s[tid] = m_old[(int64_t)b * 256 + tid];
  else           cat_s[256 + tid] = queries[(int64_t)b * 256 + (tid - 256)];
  if (kq == 0) {
    cat_s[256 + 2 * pi]     = h0;
    cat_s[256 + 2 * pi + 1] = h1;
  }
  __syncthreads();
  if (tid < 256) {
    const float* wrow = Wt_w + (int64_t)tid * 768;
    float acc = 0.f;
    #pragma unroll 8
    for (int k = 0; k < 768; k += 4) {
      float4 wv = *(const float4*)(wrow + k);
      float4 c4 = *(const float4*)(cat_s + k);
      acc += wv.x * c4.x + wv.y * c4.y + wv.z * c4.z + wv.w * c4.w;
    }
    out[(int64_t)b * 256 + tid] = fmaxf(acc + Wt_b[tid], 0.f);
  }
}

// ----------------------------------------------------------------
extern "C" void kernel_launch(void* const* d_in, const int* in_sizes, int n_in,
                              void* d_out, int out_size, void* d_ws, size_t ws_size,
                              hipStream_t stream)
{
  const float* queries   = (const float*)d_in[0];
  const float* facts     = (const float*)d_in[1];
  const int*   num_facts = (const int*)d_in[2];
  const float* m_old     = (const float*)d_in[3];
  const float* W1_w = (const float*)d_in[4];
  const float* W1_b = (const float*)d_in[5];
  const float* W2_w = (const float*)d_in[6];
  const float* W2_b = (const float*)d_in[7];
  const float* Wr_w = (const float*)d_in[8];
  const float* Ur_w = (const float*)d_in[9];
  const float* Ur_b = (const float*)d_in[10];
  const float* Wg_w = (const float*)d_in[11];
  const float* Ug_w = (const float*)d_in[12];
  const float* Ug_b = (const float*)d_in[13];
  const float* Wt_w = (const float*)d_in[14];
  const float* Wt_b = (const float*)d_in[15];
  float* out = (float*)d_out;

  char* p = (char*)d_ws;
  auto alloc = [&](size_t bytes) { char* r = p; p += (bytes + 255) & ~(size_t)255; return r; };
  f16*   W1h  = (f16*)alloc((size_t)256 * 1024 * 2);
  f16*   Wrh  = (f16*)alloc((size_t)65536 * 2);
  f16*   Wgh  = (f16*)alloc((size_t)65536 * 2);
  float* Zlog = (float*)alloc((size_t)B * T * 4);
  f16*   Frh  = (f16*)alloc((size_t)B * T * D * 2);
  f16*   Fgh  = (f16*)alloc((size_t)B * T * D * 2);

  k_convert<<<dim3(768), dim3(256), 0, stream>>>(W1_w, Wr_w, Wg_w, W1h, Wrh, Wgh);
  k_attn<<<dim3(16, 64), dim3(256), 0, stream>>>(facts, queries, m_old, W1h, W1_b, W2_w, W2_b, Zlog);
  k_factproj<<<dim3(8, 64), dim3(256), 0, stream>>>(facts, Wrh, Wgh, Ur_b, Frh, Fgh);
  k_scan_v7<<<dim3(64), dim3(512), 0, stream>>>(Zlog, num_facts, Frh, Fgh, Ur_w, Ug_w, Ug_b,
                                                m_old, queries, Wt_w, Wt_b, out);
}